// Round 1
// baseline (190.264 us; speedup 1.0000x reference)
//
#include <hip/hip_runtime.h>

// Problem constants (from reference):
//   e_src: [B=32, T=1024, F=4, C=256] fp32
//   d_src: [B=32, S=256] int32 durations in [0, 8)
//   out:   [B=32, S=256, C=256] fp32 segment means (zeros for empty segments)

#define NB 32
#define NT 1024
#define NF 4
#define NC 256
#define NS 256
#define PPB 4   // phones per block (one wave each)

__global__ __launch_bounds__(256) void FastSpeech2Pros_83769042141888_kernel(
    const float* __restrict__ e_src,   // [B, T, F, C]
    const int*   __restrict__ d_src,   // [B, S]
    float*       __restrict__ out)     // [B, S, C]
{
    const int b    = blockIdx.y;   // batch 0..31
    const int t    = threadIdx.x;  // 0..255
    const int lane = t & 63;
    const int wid  = t >> 6;       // wave 0..3

    // ---- inclusive cumsum of the 256 durations: shfl wave-scan + 2 barriers ----
    int v = d_src[b * NS + t];
    #pragma unroll
    for (int off = 1; off < 64; off <<= 1) {
        int u = __shfl_up(v, off, 64);
        if (lane >= off) v += u;
    }
    __shared__ int wsum[4];
    __shared__ int cs[NS];
    if (lane == 63) wsum[wid] = v;
    __syncthreads();
    int woff = 0;
    #pragma unroll
    for (int w = 0; w < 3; ++w) woff += (w < wid) ? wsum[w] : 0;
    cs[t] = v + woff;
    __syncthreads();

    // ---- each wave owns one phone s; lanes own channel quads ----
    const int s = blockIdx.x * PPB + wid;
    int end   = cs[s];
    int start = (s == 0) ? 0 : cs[s - 1];
    if (start > NT) start = NT;
    if (end   > NT) end   = NT;
    const int cnt = end - start;   // 0..7 (uniform across the wave)

    // Frame layout: [F][C] = 1024 floats = 256 float4; freq f at float4 idx f*64.
    const float4* base4 = (const float4*)(e_src + (size_t)b * NT * NF * NC);
    const float4* p = base4 + (size_t)start * (NF * NC / 4) + lane;

    float4 acc = make_float4(0.f, 0.f, 0.f, 0.f);
    for (int fr = 0; fr < cnt; ++fr) {
        #pragma unroll
        for (int f = 0; f < NF; ++f) {
            float4 x = p[f * 64];   // 4 independent 16B loads, offsets fold to imm
            acc.x += x.x; acc.y += x.y; acc.z += x.z; acc.w += x.w;
        }
        p += NF * NC / 4;
    }

    // mean over (frames, freq) == sum / (4*cnt); zeros if empty (acc==0, inv==0)
    const float inv = (cnt > 0) ? (1.0f / (4.0f * (float)cnt)) : 0.0f;
    float4 o;
    o.x = acc.x * inv; o.y = acc.y * inv; o.z = acc.z * inv; o.w = acc.w * inv;
    ((float4*)(out + ((size_t)b * NS + s) * NC))[lane] = o;
}

extern "C" void kernel_launch(void* const* d_in, const int* in_sizes, int n_in,
                              void* d_out, int out_size, void* d_ws, size_t ws_size,
                              hipStream_t stream) {
    const float* e_src = (const float*)d_in[0];
    const int*   d_src = (const int*)d_in[1];
    float*       out   = (float*)d_out;

    dim3 grid(NS / PPB, NB);  // 64 x 32 blocks; 4 waves/block, one phone per wave
    FastSpeech2Pros_83769042141888_kernel<<<grid, 256, 0, stream>>>(e_src, d_src, out);
}